// Round 5
// baseline (247.111 us; speedup 1.0000x reference)
//
#include <hip/hip_runtime.h>

// z = x @ W.T - b (65536x512 @ (256x512)^T) -> row-wise projection onto
// {y: |1^T y|<=S, ||y||^2<=R2}. Projection is affine per row (y = a*z + b0),
// fused into the GEMM epilogue via per-row (t, zz) reductions.
//
// R7: occupancy attack. Evidence: R3 (pipeline) null; R5 (L2-at-consume)
// regressed -> latency exposure deadly; R6 (small domains) regression =
// its extra B traffic; R5 profile: ALL pipes <10%, occupancy 39% ->
// latency-bound at 16 waves/CU. R7 doubles resident waves:
//  - BM=64, 512 threads, grid=1024 -> 4 blocks/CU.
//  - LDS = 32KB B (R2's proven glds chunk-swizzle) + 8KB XOR-swizzled A
//    = 40960 B exactly -> 4 blocks/CU by LDS.
//  - wave layout 2m x 4n (32x64/wave): acc = 32 VGPR; inner loop keeps
//    live set ~60 VGPR; __launch_bounds__(512,8) caps VGPR at 64 so
//    8 waves/EU (32/CU, 100% nominal) are achievable.
// Numerics bit-identical to R2 (same f2bf RNE, same MFMA order, same epilogue).

typedef __bf16 bf16x8 __attribute__((ext_vector_type(8)));
typedef float f32x4 __attribute__((ext_vector_type(4)));
typedef unsigned short ushort8 __attribute__((ext_vector_type(8)));

#define BM 64
#define BN 256
#define BK 64
#define THREADS 512

__device__ __forceinline__ unsigned short f2bf(float f) {
    unsigned u = __builtin_bit_cast(unsigned, f);
    u += 0x7fffu + ((u >> 16) & 1u);     // RNE
    return (unsigned short)(u >> 16);
}

// one-time: W fp32 [256][512] -> bf16 row-major in workspace
__global__ void wconv_kernel(const float* __restrict__ W,
                             unsigned short* __restrict__ Wb) {
    int i = (blockIdx.x * 256 + threadIdx.x) * 4;
    float4 v = *(const float4*)(W + i);
    ushort4 h;
    h.x = f2bf(v.x); h.y = f2bf(v.y); h.z = f2bf(v.z); h.w = f2bf(v.w);
    *(ushort4*)(Wb + i) = h;
}

__global__ __launch_bounds__(THREADS, 8)
void proj_gemm_kernel(const float* __restrict__ x,
                      const unsigned short* __restrict__ Wb,
                      const float* __restrict__ b,
                      float* __restrict__ out) {
    __shared__ alignas(16) unsigned short Bbuf[BN * BK];   // 32768 B, chunk-swizzled
    __shared__ alignas(16) unsigned short Abuf[BM * BK];   // 8192 B, XOR-swizzled

    const int tid  = threadIdx.x;
    const int lane = tid & 63;
    const int wv   = tid >> 6;        // 0..7
    const int wm   = wv >> 2;         // m-half (0..1): rows wm*32..+31
    const int wn   = wv & 3;          // n-quarter: cols wn*64..+63
    const int ln   = lane & 15;
    const int quad = lane >> 4;
    const int m0   = blockIdx.x * BM;

    // A staging: 64 rows x 8 16B-chunks (8 bf16 each); 1 chunk per thread
    const int arow = tid >> 3;        // 0..63
    const int kq   = tid & 7;         // 16B chunk within row
    const float* xbase = x + (long)(m0 + arow) * 512 + kq * 8;
    const unsigned awb = (unsigned)((arow * 128 + kq * 16) ^ ((arow & 7) << 4));

    // B staging via global_load_lds (identical to R2): 4 issues/wave, 16B/lane
    const int b_r0 = wv * 32 + (lane >> 3);          // +8 per issue j
    const int b_cg = (lane & 7) ^ (lane >> 3);       // pre-swizzled chunk in row

    f32x4 acc[2][4];
    #pragma unroll
    for (int mi = 0; mi < 2; ++mi)
        #pragma unroll
        for (int ni = 0; ni < 4; ++ni)
            acc[mi][ni] = (f32x4){0.f, 0.f, 0.f, 0.f};

    for (int kt = 0; kt < 8; ++kt) {
        const int k0 = kt * BK;
        __syncthreads();
        // stage B tile (256 x 64): 8 waves x 4 issues x 1KB, no VGPR round-trip
        #pragma unroll
        for (int j = 0; j < 4; ++j) {
            const unsigned short* src =
                Wb + (long)(b_r0 + j * 8) * 512 + k0 + b_cg * 8;
            __builtin_amdgcn_global_load_lds(
                (const __attribute__((address_space(1))) void*)src,
                (__attribute__((address_space(3))) void*)(unsigned long)(unsigned int)
                    (unsigned long)(uintptr_t)&Bbuf[(wv * 4 + j) * 512],
                16, 0, 0);
        }
        // stage A tile (64 x 64): fp32 -> bf16 -> swizzled LDS, 16B per thread
        {
            float4 v0 = *(const float4*)(xbase + k0);
            float4 v1 = *(const float4*)(xbase + k0 + 4);
            ushort8 h;
            h[0] = f2bf(v0.x); h[1] = f2bf(v0.y); h[2] = f2bf(v0.z); h[3] = f2bf(v0.w);
            h[4] = f2bf(v1.x); h[5] = f2bf(v1.y); h[6] = f2bf(v1.z); h[7] = f2bf(v1.w);
            *(ushort8*)((char*)Abuf + awb) = h;
        }
        __syncthreads();   // drains vmcnt(0)+lgkmcnt(0): glds + ds_writes visible

        #pragma unroll
        for (int ks = 0; ks < 2; ++ks) {
            bf16x8 bf[4];
            #pragma unroll
            for (int ni = 0; ni < 4; ++ni) {
                const int r  = wn * 64 + ni * 16 + ln;
                const int cc = (ks * 4 + quad) ^ (ln & 7);   // un-swizzle
                bf[ni] = *(const bf16x8*)&Bbuf[r * 64 + cc * 8];
            }
            #pragma unroll
            for (int mi = 0; mi < 2; ++mi) {
                const int row = wm * 32 + mi * 16 + ln;
                const unsigned arb =
                    (unsigned)(row * 128 + ((((ks << 2) | quad) ^ (ln & 7)) << 4));
                bf16x8 af = *(const bf16x8*)((const char*)Abuf + arb);
                #pragma unroll
                for (int ni = 0; ni < 4; ++ni)
                    acc[mi][ni] = __builtin_amdgcn_mfma_f32_16x16x32_bf16(
                        af, bf[ni], acc[mi][ni], 0, 0, 0);
            }
        }
    }

    // bias before row reductions
    float bb[4];
    #pragma unroll
    for (int ni = 0; ni < 4; ++ni) bb[ni] = b[wn * 64 + ni * 16 + ln];
    #pragma unroll
    for (int mi = 0; mi < 2; ++mi)
        #pragma unroll
        for (int ni = 0; ni < 4; ++ni)
            #pragma unroll
            for (int r = 0; r < 4; ++r)
                acc[mi][ni][r] -= bb[ni];

    __syncthreads();                  // all A/B LDS reads done before reuse
    float* P  = (float*)Abuf;         // 64 rows x {4 waves x (t,zz)} = 2 KB
    float* AB = P + 64 * 8;           // 64 x (alpha,beta) = 512 B

    // per-row partials over this wave's 64 cols (cols indexed by ni,ln)
    #pragma unroll
    for (int mi = 0; mi < 2; ++mi) {
        #pragma unroll
        for (int r = 0; r < 4; ++r) {
            float s1 = 0.f, s2 = 0.f;
            #pragma unroll
            for (int ni = 0; ni < 4; ++ni) {
                float v = acc[mi][ni][r];
                s1 += v; s2 += v * v;
            }
            #pragma unroll
            for (int off = 1; off < 16; off <<= 1) {
                s1 += __shfl_xor(s1, off, 64);
                s2 += __shfl_xor(s2, off, 64);
            }
            if (ln == 0) {
                int row = wm * 32 + mi * 16 + quad * 4 + r;
                P[row * 8 + wn * 2 + 0] = s1;
                P[row * 8 + wn * 2 + 1] = s2;
            }
        }
    }
    __syncthreads();

    // one thread per row: KKT case analysis -> (alpha, beta)
    if (tid < 64) {
        int row = tid;
        float t  = P[row*8+0] + P[row*8+2] + P[row*8+4] + P[row*8+6];
        float zz = P[row*8+1] + P[row*8+3] + P[row*8+5] + P[row*8+7];
        const float S = 0.1f, R2 = 0.02f, nf = 256.f, inv_n = 1.f / 256.f;
        float tc    = fminf(fmaxf(t, -S), S);
        float beta1 = (tc - t) * inv_n;
        float ny1   = zz + 2.f * beta1 * t + nf * beta1 * beta1;
        float alpha, beta;
        if (ny1 <= R2) {
            alpha = 1.f; beta = beta1;
        } else {
            float znorm = sqrtf(fmaxf(zz, 1e-12f));
            float scale = fminf(1.f, 0.14142135623730951f / znorm);
            if (fabsf(t) * scale <= S) {
                alpha = scale; beta = 0.f;
            } else {
                float denom = fmaxf(nf * zz - t * t, 1e-12f);
                float c  = sqrtf(5.11f / denom);             // n*R2 - S^2
                float sp = (t > 0.f) ? S : ((t < 0.f) ? -S : 0.f);
                alpha = c; beta = (sp - c * t) * inv_n;
            }
        }
        AB[row*2+0] = alpha;
        AB[row*2+1] = beta;
    }
    __syncthreads();

    // apply y = alpha*z + beta, store
    #pragma unroll
    for (int mi = 0; mi < 2; ++mi) {
        #pragma unroll
        for (int r = 0; r < 4; ++r) {
            int row = wm * 32 + mi * 16 + quad * 4 + r;
            float alpha = AB[row*2+0];
            float beta  = AB[row*2+1];
            float* orow = out + (long)(m0 + row) * 256 + wn * 64 + ln;
            #pragma unroll
            for (int ni = 0; ni < 4; ++ni)
                orow[ni*16] = alpha * acc[mi][ni][r] + beta;
        }
    }
}

extern "C" void kernel_launch(void* const* d_in, const int* in_sizes, int n_in,
                              void* d_out, int out_size, void* d_ws, size_t ws_size,
                              hipStream_t stream) {
    const float* x = (const float*)d_in[0];   // [65536, 512]
    const float* W = (const float*)d_in[1];   // [256, 512]
    const float* b = (const float*)d_in[2];   // [256]
    float* out = (float*)d_out;               // [65536, 256]
    unsigned short* Wb = (unsigned short*)d_ws; // 256KB bf16 W

    const int Dout = in_sizes[2];             // 256
    const int Din  = in_sizes[1] / Dout;      // 512
    const int Btot = in_sizes[0] / Din;       // 65536

    wconv_kernel<<<(Dout * Din) / (256 * 4), 256, 0, stream>>>(W, Wb);
    proj_gemm_kernel<<<Btot / BM, THREADS, 0, stream>>>(x, Wb, b, out);
}